// Round 1
// 157.464 us; speedup vs baseline: 1.1359x; 1.1359x over previous
//
#include <hip/hip_runtime.h>

// VQ-VAE codebook quantization — MFMA-screened, np-bit-exact.
// Screen: split-bf16 (xh+xl)(ch+cl) via mfma_f32_16x16x32_bf16, 3 terms.
// Sound window W flags possible np-argmin ambiguity (~1% of positions);
// flagged positions re-scanned with the exact np fp32 pipeline.
//
// R1 changes (latency-bound per rocprof: MfmaUtil 9.6 / VALU 20 / HBM 10%):
//  - P3: B-frags read DIRECT from global (L2-resident 128 KB), 1-tile register
//    prefetch; all 8 per-block staging barriers removed (one resident round ->
//    barrier convoys were pure exposed latency).
//  - P1: float4 global loads (32 scalar -> 8 dwordx4); LDS stride 129->132 so
//    x-tile writes are aligned b128.
//  - P6: selected codes staged into the free x-LDS then written as float4 to
//    both outputs (64 scalar stores -> 16 dwordx4 per thread).
//  - P5: exact-refine reads x from LDS instead of 64 uncoalesced global loads.

typedef short bf16x8 __attribute__((ext_vector_type(8)));
typedef float f32x4  __attribute__((ext_vector_type(4)));

#define KCODES 512
#define DDIM 64
#define HWSZ 4096
#define NPOS 131072
#define POSB 128             // positions per block
#define NBLK (NPOS / POSB)   // 1024 = 256 CU x 4 blocks/CU (one resident round)
#define OUT2_OFF 8388608
#define S_X 132              // x_lds pos-stride in floats (mult of 4: aligned b128)
#define S_X4 (S_X / 4)       // float4 stride = 33

__device__ __forceinline__ unsigned short f2bf_rne(float f) {
    unsigned u = __builtin_bit_cast(unsigned, f);
    unsigned r = u + 0x7FFFu + ((u >> 16) & 1u);
    return (unsigned short)(r >> 16);
}
__device__ __forceinline__ float bf2f(unsigned short h) {
    unsigned u = ((unsigned)h) << 16;
    return __builtin_bit_cast(float, u);
}

// numpy pairwise_sum (n=64 branch) of rounded squares, fp32, no fma.
__device__ __forceinline__ float np_sumsq64(const float* __restrict__ a) {
#pragma clang fp contract(off)
    float r0 = a[0]*a[0], r1 = a[1]*a[1], r2 = a[2]*a[2], r3 = a[3]*a[3];
    float r4 = a[4]*a[4], r5 = a[5]*a[5], r6 = a[6]*a[6], r7 = a[7]*a[7];
#pragma unroll
    for (int i = 8; i < 64; i += 8) {
        r0 += a[i+0]*a[i+0]; r1 += a[i+1]*a[i+1];
        r2 += a[i+2]*a[i+2]; r3 += a[i+3]*a[i+3];
        r4 += a[i+4]*a[i+4]; r5 += a[i+5]*a[i+5];
        r6 += a[i+6]*a[i+6]; r7 += a[i+7]*a[i+7];
    }
    return ((r0+r1)+(r2+r3)) + ((r4+r5)+(r6+r7));
}

// Prep: B-fragments (split bf16) in exact 16x16x32 B-operand layout + np cbsqr.
// ws layout: [0,128KB) bf16 frags [tile32][chunk2][split2][lane64][j8];
//            [128KB,130KB) fp32 cbsqr[512].
__global__ __launch_bounds__(256) void vq_prep(
    const float* __restrict__ cb, unsigned short* __restrict__ wsb,
    float* __restrict__ wscb)
{
    if (blockIdx.x < 128) {
        int u = blockIdx.x * 256 + threadIdx.x;   // u = k*64 + d
        int k = u >> 6, d = u & 63;
        float c = cb[u];
        unsigned short ch = f2bf_rne(c);
        float clf = c - bf2f(ch);                  // exact
        unsigned short cl = f2bf_rne(clf);
        int tile = k >> 4, n = k & 15;
        int chunk = d >> 5, quad = (d >> 3) & 3, j = d & 7;
        int lane = quad * 16 + n;                  // B: lane holds B[k=q*8+j][n]
        size_t base = ((((size_t)tile*2 + chunk)*2 + 0)*64 + lane)*8 + j;
        wsb[base]       = (unsigned short)ch;
        wsb[base + 512] = (unsigned short)cl;      // split stride = 64*8
    } else {
        int k = (blockIdx.x - 128) * 256 + threadIdx.x;
        if (k < KCODES) wscb[k] = np_sumsq64(cb + k * DDIM);
    }
}

__global__ __launch_bounds__(256, 4) void vq_main(
    const float* __restrict__ z, const float* __restrict__ cb,
    const unsigned short* __restrict__ wsb, const float* __restrict__ wscb,
    float* __restrict__ out)
{
#pragma clang fp contract(off)
    __shared__ float4 s_xbuf4[DDIM * S_X4];   // 33792 B: x tile, reused for codes in P6
    __shared__ float s_cbsqr[KCODES];
    __shared__ float s_xsqr[POSB];
    __shared__ float s_part[2 * POSB];
    __shared__ int   s_idx[POSB];
    __shared__ int   s_flist[POSB];
    __shared__ int   s_cnt;
    float* s_regA = (float*)s_xbuf4;
    // total LDS ~38.4 KB -> 4 blocks/CU (16 waves/CU)

    const int tid = threadIdx.x;
    const int wv = tid >> 6, ln = tid & 63;
    const int m = ln & 15, q = ln >> 4;
    const int n0 = blockIdx.x * POSB;
    const long gbase = (long)(n0 >> 12) * (DDIM * HWSZ) + (n0 & 4095);

    if (tid == 0) s_cnt = 0;
    s_cbsqr[tid] = wscb[tid];
    s_cbsqr[tid + 256] = wscb[tid + 256];

    // ---- phase 1: z -> x_lds, d-major [d][pos], float4 coalesced ----
    {
        const float4* z4 = (const float4*)(z + gbase);  // gbase mult of 128 -> aligned
#pragma unroll
        for (int i = 0; i < 8; ++i) {
            int v = i * 256 + tid;
            int d = v >> 5, p4 = v & 31;
            s_xbuf4[d * S_X4 + p4] = z4[d * (HWSZ / 4) + p4];
        }
    }
    __syncthreads();

    // ---- phase 2a: np xsqr partials (thread -> (p, h)) ----
    {
        int p = tid & 127, h = tid >> 7;
        float r0 = 0.f, r1 = 0.f, r2 = 0.f, r3 = 0.f;
#pragma unroll
        for (int i = 0; i < 8; ++i) {
            float a0 = s_regA[(8*i + 4*h + 0) * S_X + p];
            float a1 = s_regA[(8*i + 4*h + 1) * S_X + p];
            float a2 = s_regA[(8*i + 4*h + 2) * S_X + p];
            float a3 = s_regA[(8*i + 4*h + 3) * S_X + p];
            r0 += a0*a0; r1 += a1*a1; r2 += a2*a2; r3 += a3*a3;
        }
        s_part[h * POSB + p] = (r0 + r1) + (r2 + r3);
    }

    // ---- phase 2b: A-fragments (per wave: 2 row-tiles x 2 K-chunks, split) ----
    bf16x8 Ah[4], Al[4];
#pragma unroll
    for (int rt = 0; rt < 2; ++rt)
#pragma unroll
        for (int c = 0; c < 2; ++c) {
            int pos = wv * 32 + rt * 16 + m;
            bf16x8 ah, al;
#pragma unroll
            for (int j = 0; j < 8; ++j) {
                float xv = s_regA[(c*32 + q*8 + j) * S_X + pos];
                unsigned short hh = f2bf_rne(xv);
                float lo = xv - bf2f(hh);          // exact
                ah[j] = (short)hh;
                al[j] = (short)f2bf_rne(lo);
            }
            Ah[rt*2 + c] = ah; Al[rt*2 + c] = al;
        }
    __syncthreads();
    if (tid < POSB) s_xsqr[tid] = s_part[tid] + s_part[POSB + tid]; // np (A+B)
    __syncthreads();   // s_xsqr visible to all (P4 readers); P3 below is barrier-free

    // ---- phase 3: screen all 512 codes, B-frags direct from global (L2-hot),
    //      1-tile register prefetch, NO barriers ----
    float m1[8], m2[8]; int t1[8];
#pragma unroll
    for (int i = 0; i < 8; ++i) { m1[i] = 3.4e38f; m2[i] = 3.4e38f; t1[i] = 0; }

    {
        const unsigned short* wbl = wsb + ln * 8;   // per-lane frag base
        bf16x8 pBh0 = *(const bf16x8*)(wbl + 0);
        bf16x8 pBl0 = *(const bf16x8*)(wbl + 512);
        bf16x8 pBh1 = *(const bf16x8*)(wbl + 1024);
        bf16x8 pBl1 = *(const bf16x8*)(wbl + 1536);
#pragma unroll 4
        for (int t = 0; t < 32; ++t) {
            bf16x8 Bh0 = pBh0, Bl0 = pBl0, Bh1 = pBh1, Bl1 = pBl1;
            if (t < 31) {                            // prefetch next tile (16B x4, L2)
                const unsigned short* nb = wbl + (t + 1) * 2048;
                pBh0 = *(const bf16x8*)(nb + 0);
                pBl0 = *(const bf16x8*)(nb + 512);
                pBh1 = *(const bf16x8*)(nb + 1024);
                pBl1 = *(const bf16x8*)(nb + 1536);
            }
            float cbv = s_cbsqr[t * 16 + m];
#pragma unroll
            for (int rt = 0; rt < 2; ++rt) {
                f32x4 acc = {0.f, 0.f, 0.f, 0.f};
                acc = __builtin_amdgcn_mfma_f32_16x16x32_bf16(Al[rt*2+0], Bh0, acc, 0,0,0);
                acc = __builtin_amdgcn_mfma_f32_16x16x32_bf16(Ah[rt*2+0], Bl0, acc, 0,0,0);
                acc = __builtin_amdgcn_mfma_f32_16x16x32_bf16(Ah[rt*2+0], Bh0, acc, 0,0,0);
                acc = __builtin_amdgcn_mfma_f32_16x16x32_bf16(Al[rt*2+1], Bh1, acc, 0,0,0);
                acc = __builtin_amdgcn_mfma_f32_16x16x32_bf16(Ah[rt*2+1], Bl1, acc, 0,0,0);
                acc = __builtin_amdgcn_mfma_f32_16x16x32_bf16(Ah[rt*2+1], Bh1, acc, 0,0,0);
#pragma unroll
                for (int r = 0; r < 4; ++r) {
                    float sc = fmaf(-2.f, acc[r], cbv);
                    int cell = rt * 4 + r;
                    bool lt = sc < m1[cell];
                    m2[cell] = fminf(m2[cell], lt ? m1[cell] : sc);
                    if (lt) { m1[cell] = sc; t1[cell] = t; }
                }
            }
        }
    }

    // ---- phase 4: per-position reduce over 16 lanes; flag ambiguity ----
#pragma unroll
    for (int cell = 0; cell < 8; ++cell) {
        int rt = cell >> 2, r = cell & 3;
        float v1 = m1[cell], v2 = m2[cell];
        int i1 = t1[cell] * 16 + m;
#pragma unroll
        for (int s = 1; s < 16; s <<= 1) {
            float o1 = __shfl_xor(v1, s);
            float o2 = __shfl_xor(v2, s);
            int   oi = __shfl_xor(i1, s);
            bool take = (o1 < v1) || (o1 == v1 && oi < i1);
            float lose = take ? v1 : o1;
            if (take) { v1 = o1; i1 = oi; }
            v2 = fminf(fminf(v2, o2), lose);
        }
        if (m == 0) {
            int pos = wv * 32 + rt * 16 + q * 4 + r;
            float xs = s_xsqr[pos];
            float sx = 8.0f * sqrtf(xs) * 1.01f;       // >= sum |x_d|
            float amax = 0.00196f * sx + 0.01f;        // >= sum|x c| + margin
            float eps = 1.5f * (3.0f * 1.52587890625e-5f * 0.00196f * sx
                                + 500.f * 5.96e-8f * amax);
            float delta = 2.4e-7f * (xs + 1.0f) + 64.f * 1.2e-7f * amax;
            float W = 2.f * eps + 2.f * delta + 1e-9f;
            int flag = (v2 - v1 <= W) ? (1 << 30) : 0;
            s_idx[pos] = i1 | flag;
        }
    }
    __syncthreads();
    if (tid < POSB) {
        if (s_idx[tid] & (1 << 30)) {
            int slot = atomicAdd(&s_cnt, 1);
            s_flist[slot] = tid;
        }
    }
    __syncthreads();

    // ---- phase 5: np-exact refine of flagged positions (x read from LDS) ----
    const int cnt = s_cnt;
    for (int i = wv; i < cnt; i += 4) {
        int p = __builtin_amdgcn_readfirstlane(s_flist[i]);
        float xv = s_regA[ln * S_X + p];             // lane ln holds x[d=ln]
        float xs = s_xsqr[p];
        float dot[8];
#pragma unroll
        for (int j = 0; j < 8; ++j) dot[j] = 0.f;
        const float* crow = cb + (ln * 8) * DDIM;    // lane's 8 codes
        for (int dc = 0; dc < 16; ++dc) {
            float x0 = __shfl(xv, dc*4 + 0);
            float x1 = __shfl(xv, dc*4 + 1);
            float x2 = __shfl(xv, dc*4 + 2);
            float x3 = __shfl(xv, dc*4 + 3);
#pragma unroll
            for (int j = 0; j < 8; ++j) {
                float4 cv = *(const float4*)(crow + j * DDIM + dc * 4);
                dot[j] = fmaf(x0, cv.x, dot[j]);
                dot[j] = fmaf(x1, cv.y, dot[j]);
                dot[j] = fmaf(x2, cv.z, dot[j]);
                dot[j] = fmaf(x3, cv.w, dot[j]);
            }
        }
        float bv = 3.4e38f; int bi = 0;
#pragma unroll
        for (int j = 0; j < 8; ++j) {
            int k = ln * 8 + j;
            float tt = s_cbsqr[k] + xs;
            float e = fmaf(-2.f, dot[j], tt);
            if (e < bv) { bv = e; bi = k; }
        }
#pragma unroll
        for (int s = 1; s < 64; s <<= 1) {
            float ov = __shfl_xor(bv, s); int oi = __shfl_xor(bi, s);
            if (ov < bv || (ov == bv && oi < bi)) { bv = ov; bi = oi; }
        }
        if (ln == 0) s_idx[p] = bi;
    }
    __syncthreads();   // P5 LDS reads done; s_idx final -> safe to overwrite s_regA

    // ---- phase 6a: stage selected code rows into LDS, d-major [d][pos] ----
    {
        int p = tid & 127, hf = tid >> 7;
        int idx = s_idx[p] & 0x3FFFFFFF;
        const float4* crow4 = (const float4*)(cb + idx * DDIM + hf * 32);
#pragma unroll
        for (int j4 = 0; j4 < 8; ++j4) {
            float4 cv = crow4[j4];
            int d = hf * 32 + j4 * 4;
            s_regA[(d + 0) * S_X + p] = cv.x;   // fixed d per instr, p per lane:
            s_regA[(d + 1) * S_X + p] = cv.y;   // consecutive banks, conflict-free
            s_regA[(d + 2) * S_X + p] = cv.z;
            s_regA[(d + 3) * S_X + p] = cv.w;
        }
    }
    __syncthreads();

    // ---- phase 6b: float4 writeback to both outputs (NCHW) ----
    {
        float4* o4 = (float4*)(out + gbase);
#pragma unroll
        for (int i = 0; i < 8; ++i) {
            int v = i * 256 + tid;
            int d = v >> 5, p4 = v & 31;
            float4 val = s_xbuf4[d * S_X4 + p4];
            size_t off = (size_t)d * (HWSZ / 4) + p4;
            o4[off] = val;
            o4[off + (OUT2_OFF / 4)] = val;
        }
    }
}

extern "C" void kernel_launch(void* const* d_in, const int* in_sizes, int n_in,
                              void* d_out, int out_size, void* d_ws, size_t ws_size,
                              hipStream_t stream) {
    const float* z  = (const float*)d_in[0];   // [32,64,64,64] fp32
    const float* cb = (const float*)d_in[1];   // [512,64] fp32
    float* out = (float*)d_out;                // 2 * 8388608 fp32
    unsigned short* wsb = (unsigned short*)d_ws;            // 128 KB frags
    float* wscb = (float*)((char*)d_ws + 131072);           // 2 KB cbsqr
    vq_prep<<<130, 256, 0, stream>>>(cb, wsb, wscb);
    vq_main<<<NBLK, 256, 0, stream>>>(z, cb, wsb, wscb, out);
}

// Round 4
// 150.079 us; speedup vs baseline: 1.1918x; 1.0492x over previous
//
#include <hip/hip_runtime.h>

// VQ-VAE codebook quantization — MFMA-screened, np-bit-exact.
// Screen: split-bf16 (xh+xl)(ch+cl) via mfma_f32_16x16x32_bf16, 3 terms.
// Sound window W flags possible np-argmin ambiguity (~1% of positions);
// flagged positions re-scanned with the exact np fp32 pipeline.
//
// R4 = R2 resubmitted verbatim (R2/R3 benches were broker infra failures;
// source audited for hang/fault vectors: none — P3 reads bounded at 128 KB,
// no new barriers/loops vs R1 which benched clean).
// Post-mortem of R1 still governs: R1's explicit 1-tile B-frag prefetch
// pushed reg pressure past the launch_bounds(256,4) cap of 128 unified
// VGPRs -> compiler spilled m1/m2/t1 (24 dwords/thread) to scratch.
// Signature: WRITE_SIZE 65536->90112 KB (+24 MiB = 96 B/thread). Fix:
// drop the explicit prefetch (-16 VGPRs), unroll 2, rely on 4 waves/SIMD
// TLP + compiler scheduling to hide the L2 latency of per-tile frag loads.
// Kept from R1: barrier-free P3 (direct-global L2-hot B-frags), float4 P1
// load / P6 writeback via LDS staging, P5 reads x from LDS.

typedef short bf16x8 __attribute__((ext_vector_type(8)));
typedef float f32x4  __attribute__((ext_vector_type(4)));

#define KCODES 512
#define DDIM 64
#define HWSZ 4096
#define NPOS 131072
#define POSB 128             // positions per block
#define NBLK (NPOS / POSB)   // 1024 = 256 CU x 4 blocks/CU (one resident round)
#define OUT2_OFF 8388608
#define S_X 132              // x_lds pos-stride in floats (mult of 4: aligned b128)
#define S_X4 (S_X / 4)       // float4 stride = 33

__device__ __forceinline__ unsigned short f2bf_rne(float f) {
    unsigned u = __builtin_bit_cast(unsigned, f);
    unsigned r = u + 0x7FFFu + ((u >> 16) & 1u);
    return (unsigned short)(r >> 16);
}
__device__ __forceinline__ float bf2f(unsigned short h) {
    unsigned u = ((unsigned)h) << 16;
    return __builtin_bit_cast(float, u);
}

// numpy pairwise_sum (n=64 branch) of rounded squares, fp32, no fma.
__device__ __forceinline__ float np_sumsq64(const float* __restrict__ a) {
#pragma clang fp contract(off)
    float r0 = a[0]*a[0], r1 = a[1]*a[1], r2 = a[2]*a[2], r3 = a[3]*a[3];
    float r4 = a[4]*a[4], r5 = a[5]*a[5], r6 = a[6]*a[6], r7 = a[7]*a[7];
#pragma unroll
    for (int i = 8; i < 64; i += 8) {
        r0 += a[i+0]*a[i+0]; r1 += a[i+1]*a[i+1];
        r2 += a[i+2]*a[i+2]; r3 += a[i+3]*a[i+3];
        r4 += a[i+4]*a[i+4]; r5 += a[i+5]*a[i+5];
        r6 += a[i+6]*a[i+6]; r7 += a[i+7]*a[i+7];
    }
    return ((r0+r1)+(r2+r3)) + ((r4+r5)+(r6+r7));
}

// Prep: B-fragments (split bf16) in exact 16x16x32 B-operand layout + np cbsqr.
// ws layout: [0,128KB) bf16 frags [tile32][chunk2][split2][lane64][j8];
//            [128KB,130KB) fp32 cbsqr[512].
__global__ __launch_bounds__(256) void vq_prep(
    const float* __restrict__ cb, unsigned short* __restrict__ wsb,
    float* __restrict__ wscb)
{
    if (blockIdx.x < 128) {
        int u = blockIdx.x * 256 + threadIdx.x;   // u = k*64 + d
        int k = u >> 6, d = u & 63;
        float c = cb[u];
        unsigned short ch = f2bf_rne(c);
        float clf = c - bf2f(ch);                  // exact
        unsigned short cl = f2bf_rne(clf);
        int tile = k >> 4, n = k & 15;
        int chunk = d >> 5, quad = (d >> 3) & 3, j = d & 7;
        int lane = quad * 16 + n;                  // B: lane holds B[k=q*8+j][n]
        size_t base = ((((size_t)tile*2 + chunk)*2 + 0)*64 + lane)*8 + j;
        wsb[base]       = (unsigned short)ch;
        wsb[base + 512] = (unsigned short)cl;      // split stride = 64*8
    } else {
        int k = (blockIdx.x - 128) * 256 + threadIdx.x;
        if (k < KCODES) wscb[k] = np_sumsq64(cb + k * DDIM);
    }
}

__global__ __launch_bounds__(256, 4) void vq_main(
    const float* __restrict__ z, const float* __restrict__ cb,
    const unsigned short* __restrict__ wsb, const float* __restrict__ wscb,
    float* __restrict__ out)
{
#pragma clang fp contract(off)
    __shared__ float4 s_xbuf4[DDIM * S_X4];   // 33792 B: x tile, reused for codes in P6
    __shared__ float s_cbsqr[KCODES];
    __shared__ float s_xsqr[POSB];
    __shared__ float s_part[2 * POSB];
    __shared__ int   s_idx[POSB];
    __shared__ int   s_flist[POSB];
    __shared__ int   s_cnt;
    float* s_regA = (float*)s_xbuf4;
    // total LDS ~38.9 KB -> 4 blocks/CU (16 waves/CU)

    const int tid = threadIdx.x;
    const int wv = tid >> 6, ln = tid & 63;
    const int m = ln & 15, q = ln >> 4;
    const int n0 = blockIdx.x * POSB;
    const long gbase = (long)(n0 >> 12) * (DDIM * HWSZ) + (n0 & 4095);

    if (tid == 0) s_cnt = 0;
    s_cbsqr[tid] = wscb[tid];
    s_cbsqr[tid + 256] = wscb[tid + 256];

    // ---- phase 1: z -> x_lds, d-major [d][pos], float4 coalesced ----
    {
        const float4* z4 = (const float4*)(z + gbase);  // gbase mult of 128 -> aligned
#pragma unroll
        for (int i = 0; i < 8; ++i) {
            int v = i * 256 + tid;
            int d = v >> 5, p4 = v & 31;
            s_xbuf4[d * S_X4 + p4] = z4[d * (HWSZ / 4) + p4];
        }
    }
    __syncthreads();

    // ---- phase 2a: np xsqr partials (thread -> (p, h)) ----
    {
        int p = tid & 127, h = tid >> 7;
        float r0 = 0.f, r1 = 0.f, r2 = 0.f, r3 = 0.f;
#pragma unroll
        for (int i = 0; i < 8; ++i) {
            float a0 = s_regA[(8*i + 4*h + 0) * S_X + p];
            float a1 = s_regA[(8*i + 4*h + 1) * S_X + p];
            float a2 = s_regA[(8*i + 4*h + 2) * S_X + p];
            float a3 = s_regA[(8*i + 4*h + 3) * S_X + p];
            r0 += a0*a0; r1 += a1*a1; r2 += a2*a2; r3 += a3*a3;
        }
        s_part[h * POSB + p] = (r0 + r1) + (r2 + r3);
    }

    // ---- phase 2b: A-fragments (per wave: 2 row-tiles x 2 K-chunks, split) ----
    bf16x8 Ah[4], Al[4];
#pragma unroll
    for (int rt = 0; rt < 2; ++rt)
#pragma unroll
        for (int c = 0; c < 2; ++c) {
            int pos = wv * 32 + rt * 16 + m;
            bf16x8 ah, al;
#pragma unroll
            for (int j = 0; j < 8; ++j) {
                float xv = s_regA[(c*32 + q*8 + j) * S_X + pos];
                unsigned short hh = f2bf_rne(xv);
                float lo = xv - bf2f(hh);          // exact
                ah[j] = (short)hh;
                al[j] = (short)f2bf_rne(lo);
            }
            Ah[rt*2 + c] = ah; Al[rt*2 + c] = al;
        }
    __syncthreads();
    if (tid < POSB) s_xsqr[tid] = s_part[tid] + s_part[POSB + tid]; // np (A+B)
    __syncthreads();   // s_xsqr visible to all (P4 readers); P3 below is barrier-free

    // ---- phase 3: screen all 512 codes, B-frags direct from global (L2-hot),
    //      no explicit prefetch (reg budget), no barriers ----
    float m1[8], m2[8]; int t1[8];
#pragma unroll
    for (int i = 0; i < 8; ++i) { m1[i] = 3.4e38f; m2[i] = 3.4e38f; t1[i] = 0; }

    {
        const unsigned short* wbl = wsb + ln * 8;   // per-lane frag base
#pragma unroll 2
        for (int t = 0; t < 32; ++t) {
            const unsigned short* nb = wbl + t * 2048;
            bf16x8 Bh0 = *(const bf16x8*)(nb + 0);
            bf16x8 Bl0 = *(const bf16x8*)(nb + 512);
            bf16x8 Bh1 = *(const bf16x8*)(nb + 1024);
            bf16x8 Bl1 = *(const bf16x8*)(nb + 1536);
            float cbv = s_cbsqr[t * 16 + m];
#pragma unroll
            for (int rt = 0; rt < 2; ++rt) {
                f32x4 acc = {0.f, 0.f, 0.f, 0.f};
                acc = __builtin_amdgcn_mfma_f32_16x16x32_bf16(Al[rt*2+0], Bh0, acc, 0,0,0);
                acc = __builtin_amdgcn_mfma_f32_16x16x32_bf16(Ah[rt*2+0], Bl0, acc, 0,0,0);
                acc = __builtin_amdgcn_mfma_f32_16x16x32_bf16(Ah[rt*2+0], Bh0, acc, 0,0,0);
                acc = __builtin_amdgcn_mfma_f32_16x16x32_bf16(Al[rt*2+1], Bh1, acc, 0,0,0);
                acc = __builtin_amdgcn_mfma_f32_16x16x32_bf16(Ah[rt*2+1], Bl1, acc, 0,0,0);
                acc = __builtin_amdgcn_mfma_f32_16x16x32_bf16(Ah[rt*2+1], Bh1, acc, 0,0,0);
#pragma unroll
                for (int r = 0; r < 4; ++r) {
                    float sc = fmaf(-2.f, acc[r], cbv);
                    int cell = rt * 4 + r;
                    bool lt = sc < m1[cell];
                    m2[cell] = fminf(m2[cell], lt ? m1[cell] : sc);
                    if (lt) { m1[cell] = sc; t1[cell] = t; }
                }
            }
        }
    }

    // ---- phase 4: per-position reduce over 16 lanes; flag ambiguity ----
#pragma unroll
    for (int cell = 0; cell < 8; ++cell) {
        int rt = cell >> 2, r = cell & 3;
        float v1 = m1[cell], v2 = m2[cell];
        int i1 = t1[cell] * 16 + m;
#pragma unroll
        for (int s = 1; s < 16; s <<= 1) {
            float o1 = __shfl_xor(v1, s);
            float o2 = __shfl_xor(v2, s);
            int   oi = __shfl_xor(i1, s);
            bool take = (o1 < v1) || (o1 == v1 && oi < i1);
            float lose = take ? v1 : o1;
            if (take) { v1 = o1; i1 = oi; }
            v2 = fminf(fminf(v2, o2), lose);
        }
        if (m == 0) {
            int pos = wv * 32 + rt * 16 + q * 4 + r;
            float xs = s_xsqr[pos];
            float sx = 8.0f * sqrtf(xs) * 1.01f;       // >= sum |x_d|
            float amax = 0.00196f * sx + 0.01f;        // >= sum|x c| + margin
            float eps = 1.5f * (3.0f * 1.52587890625e-5f * 0.00196f * sx
                                + 500.f * 5.96e-8f * amax);
            float delta = 2.4e-7f * (xs + 1.0f) + 64.f * 1.2e-7f * amax;
            float W = 2.f * eps + 2.f * delta + 1e-9f;
            int flag = (v2 - v1 <= W) ? (1 << 30) : 0;
            s_idx[pos] = i1 | flag;
        }
    }
    __syncthreads();
    if (tid < POSB) {
        if (s_idx[tid] & (1 << 30)) {
            int slot = atomicAdd(&s_cnt, 1);
            s_flist[slot] = tid;
        }
    }
    __syncthreads();

    // ---- phase 5: np-exact refine of flagged positions (x read from LDS) ----
    const int cnt = s_cnt;
    for (int i = wv; i < cnt; i += 4) {
        int p = __builtin_amdgcn_readfirstlane(s_flist[i]);
        float xv = s_regA[ln * S_X + p];             // lane ln holds x[d=ln]
        float xs = s_xsqr[p];
        float dot[8];
#pragma unroll
        for (int j = 0; j < 8; ++j) dot[j] = 0.f;
        const float* crow = cb + (ln * 8) * DDIM;    // lane's 8 codes
        for (int dc = 0; dc < 16; ++dc) {
            float x0 = __shfl(xv, dc*4 + 0);
            float x1 = __shfl(xv, dc*4 + 1);
            float x2 = __shfl(xv, dc*4 + 2);
            float x3 = __shfl(xv, dc*4 + 3);
#pragma unroll
            for (int j = 0; j < 8; ++j) {
                float4 cv = *(const float4*)(crow + j * DDIM + dc * 4);
                dot[j] = fmaf(x0, cv.x, dot[j]);
                dot[j] = fmaf(x1, cv.y, dot[j]);
                dot[j] = fmaf(x2, cv.z, dot[j]);
                dot[j] = fmaf(x3, cv.w, dot[j]);
            }
        }
        float bv = 3.4e38f; int bi = 0;
#pragma unroll
        for (int j = 0; j < 8; ++j) {
            int k = ln * 8 + j;
            float tt = s_cbsqr[k] + xs;
            float e = fmaf(-2.f, dot[j], tt);
            if (e < bv) { bv = e; bi = k; }
        }
#pragma unroll
        for (int s = 1; s < 64; s <<= 1) {
            float ov = __shfl_xor(bv, s); int oi = __shfl_xor(bi, s);
            if (ov < bv || (ov == bv && oi < bi)) { bv = ov; bi = oi; }
        }
        if (ln == 0) s_idx[p] = bi;
    }
    __syncthreads();   // P5 LDS reads done; s_idx final -> safe to overwrite s_regA

    // ---- phase 6a: stage selected code rows into LDS, d-major [d][pos] ----
    {
        int p = tid & 127, hf = tid >> 7;
        int idx = s_idx[p] & 0x3FFFFFFF;
        const float4* crow4 = (const float4*)(cb + idx * DDIM + hf * 32);
#pragma unroll
        for (int j4 = 0; j4 < 8; ++j4) {
            float4 cv = crow4[j4];
            int d = hf * 32 + j4 * 4;
            s_regA[(d + 0) * S_X + p] = cv.x;   // fixed d per instr, p per lane:
            s_regA[(d + 1) * S_X + p] = cv.y;   // consecutive banks, conflict-free
            s_regA[(d + 2) * S_X + p] = cv.z;
            s_regA[(d + 3) * S_X + p] = cv.w;
        }
    }
    __syncthreads();

    // ---- phase 6b: float4 writeback to both outputs (NCHW) ----
    {
        float4* o4 = (float4*)(out + gbase);
#pragma unroll
        for (int i = 0; i < 8; ++i) {
            int v = i * 256 + tid;
            int d = v >> 5, p4 = v & 31;
            float4 val = s_xbuf4[d * S_X4 + p4];
            size_t off = (size_t)d * (HWSZ / 4) + p4;
            o4[off] = val;
            o4[off + (OUT2_OFF / 4)] = val;
        }
    }
}

extern "C" void kernel_launch(void* const* d_in, const int* in_sizes, int n_in,
                              void* d_out, int out_size, void* d_ws, size_t ws_size,
                              hipStream_t stream) {
    const float* z  = (const float*)d_in[0];   // [32,64,64,64] fp32
    const float* cb = (const float*)d_in[1];   // [512,64] fp32
    float* out = (float*)d_out;                // 2 * 8388608 fp32
    unsigned short* wsb = (unsigned short*)d_ws;            // 128 KB frags
    float* wscb = (float*)((char*)d_ws + 131072);           // 2 KB cbsqr
    vq_prep<<<130, 256, 0, stream>>>(cb, wsb, wscb);
    vq_main<<<NBLK, 256, 0, stream>>>(z, cb, wsb, wscb, out);
}